// Round 1
// baseline (736.364 us; speedup 1.0000x reference)
//
#include <hip/hip_runtime.h>

// ---------------------------------------------------------------------------
// LlamaAttention_Tender: hidden(2048x4096) -> QKV proj -> RoPE -> int8 qdq(K,V)
// -> GQA causal attention (32 q-heads, 8 kv-heads, D=128) -> out proj.
// All matmuls via bf16 16x16x32 MFMA, fp32 accum. fp32 inputs cast to bf16.
// ---------------------------------------------------------------------------

#define S_LEN 2048
#define HID 4096
#define NH 32
#define NKV 8
#define HD 128
#define QKV_N 6144   // 4096 q + 1024 k + 1024 v

typedef __bf16 bf16x8 __attribute__((ext_vector_type(8)));
typedef float f32x4 __attribute__((ext_vector_type(4)));

__device__ __forceinline__ unsigned short f2b(float f) {
  unsigned int u = __float_as_uint(f);
  u += 0x7fffu + ((u >> 16) & 1u);   // round-to-nearest-even
  return (unsigned short)(u >> 16);
}
__device__ __forceinline__ float b2f(unsigned short h) {
  return __uint_as_float(((unsigned int)h) << 16);
}
// async global->LDS, 16B per lane. LDS dst must be wave-uniform (lane*16 implicit).
__device__ __forceinline__ void gl_lds16(const void* g, void* l) {
  __builtin_amdgcn_global_load_lds(
      (__attribute__((address_space(1))) void*)g,
      (__attribute__((address_space(3))) void*)l, 16, 0, 0);
}

// ---------------------------------------------------------------- cast fp32->bf16
__global__ __launch_bounds__(256) void cast_kernel(const float* __restrict__ src,
                                                   unsigned short* __restrict__ dst,
                                                   int n4) {
  int i = blockIdx.x * 256 + threadIdx.x;
  if (i >= n4) return;
  float4 v = ((const float4*)src)[i];
  ushort4 o;
  o.x = f2b(v.x); o.y = f2b(v.y); o.z = f2b(v.z); o.w = f2b(v.w);
  ((ushort4*)dst)[i] = o;
}

// ------------------------------------------------------- B^T GEMM (m97 structure)
// C[M,N] = A[M,K] * B[N,K]^T, 128x128 tile, BK=32, 256 thr (4 waves, 64x64 each).
template <int OUT_BF16>
__global__ __launch_bounds__(256) void gemm_bt(const unsigned short* __restrict__ A,
                                               const unsigned short* __restrict__ B,
                                               void* __restrict__ Cout,
                                               int M, int N, int K) {
  __shared__ __align__(16) unsigned short As[128 * 32];
  __shared__ __align__(16) unsigned short Bs[128 * 32];
  const int tid = threadIdx.x;
  const int lane = tid & 63, wave = tid >> 6;
  const int quad = lane >> 4, l16 = lane & 15;
  const long row0 = (long)blockIdx.y * 128;
  const long col0 = (long)blockIdx.x * 128;
  const int wr = (wave >> 1) * 64, wc = (wave & 1) * 64;

  f32x4 acc[4][4] = {};

  // staging map: call c covers flat elems [c*2048, c*2048+2048), 8 elems/lane
  const int e0 = tid * 8;
  const int r0s = e0 >> 5, c0s = e0 & 31;
  const int r1s = (e0 + 2048) >> 5;  // c1s == c0s
  const unsigned short* Ap0 = A + (row0 + r0s) * (long)K + c0s;
  const unsigned short* Ap1 = A + (row0 + r1s) * (long)K + c0s;
  const unsigned short* Bp0 = B + (col0 + r0s) * (long)K + c0s;
  const unsigned short* Bp1 = B + (col0 + r1s) * (long)K + c0s;
  unsigned short* AsD0 = As + wave * 512;
  unsigned short* AsD1 = As + 2048 + wave * 512;
  unsigned short* BsD0 = Bs + wave * 512;
  unsigned short* BsD1 = Bs + 2048 + wave * 512;

  for (int k0 = 0; k0 < K; k0 += 32) {
    __syncthreads();
    gl_lds16(Ap0 + k0, AsD0);
    gl_lds16(Ap1 + k0, AsD1);
    gl_lds16(Bp0 + k0, BsD0);
    gl_lds16(Bp1 + k0, BsD1);
    __syncthreads();
    bf16x8 af[4], bf[4];
#pragma unroll
    for (int mi = 0; mi < 4; ++mi)
      af[mi] = *(const bf16x8*)&As[(wr + mi * 16 + l16) * 32 + quad * 8];
#pragma unroll
    for (int ni = 0; ni < 4; ++ni)
      bf[ni] = *(const bf16x8*)&Bs[(wc + ni * 16 + l16) * 32 + quad * 8];
#pragma unroll
    for (int mi = 0; mi < 4; ++mi)
#pragma unroll
      for (int ni = 0; ni < 4; ++ni)
        acc[mi][ni] = __builtin_amdgcn_mfma_f32_16x16x32_bf16(af[mi], bf[ni], acc[mi][ni], 0, 0, 0);
  }
#pragma unroll
  for (int mi = 0; mi < 4; ++mi)
#pragma unroll
    for (int ni = 0; ni < 4; ++ni)
#pragma unroll
      for (int r = 0; r < 4; ++r) {
        long row = row0 + wr + mi * 16 + quad * 4 + r;
        long col = col0 + wc + ni * 16 + l16;
        float v = acc[mi][ni][r];
        if (OUT_BF16) ((unsigned short*)Cout)[row * N + col] = f2b(v);
        else          ((float*)Cout)[row * N + col] = v;
      }
}

// ------------------------------------------- RoPE + sym int8 quant-dequant + split
// qkv[2048][6144] bf16 -> Qb[32][2048][128], Kb[8][2048][128], Vb[8][2048][128]
__global__ __launch_bounds__(256) void postproc(const unsigned short* __restrict__ qkv,
                                                const int* __restrict__ pos_ids,
                                                unsigned short* __restrict__ Qb,
                                                unsigned short* __restrict__ Kb,
                                                unsigned short* __restrict__ Vb) {
  const int s = blockIdx.x;
  const int lane = threadIdx.x & 63, wave = threadIdx.x >> 6;
  const float pos = (float)pos_ids[s];
  // inv_freq = 10000^(-lane/64) = exp(-lane * ln(10000)/64); pair (d, d+64)
  const float invf = expf(-(float)lane * 0.14391156831212787f);
  const float ang = pos * invf;
  const float ca = cosf(ang), sa = sinf(ang);

  for (int r = wave; r < 48; r += 4) {
    if (r < 32) {                 // Q head r: rope only
      const unsigned short* src = qkv + (long)s * QKV_N + r * HD;
      float x0 = b2f(src[lane]), x1 = b2f(src[lane + 64]);
      unsigned short* dst = Qb + ((long)r * S_LEN + s) * HD;
      dst[lane]      = f2b(x0 * ca - x1 * sa);
      dst[lane + 64] = f2b(x1 * ca + x0 * sa);
    } else if (r < 40) {          // K head r-32: rope then quant-dequant
      int h = r - 32;
      const unsigned short* src = qkv + (long)s * QKV_N + 4096 + h * HD;
      float x0 = b2f(src[lane]), x1 = b2f(src[lane + 64]);
      float y0 = x0 * ca - x1 * sa;
      float y1 = x1 * ca + x0 * sa;
      float m = fmaxf(fabsf(y0), fabsf(y1));
      for (int off = 32; off; off >>= 1) m = fmaxf(m, __shfl_xor(m, off, 64));
      float scale = fmaxf(m / 127.0f, 1e-9f);
      float q0 = fminf(fmaxf(rintf(y0 / scale), -128.f), 127.f);
      float q1 = fminf(fmaxf(rintf(y1 / scale), -128.f), 127.f);
      unsigned short* dst = Kb + ((long)h * S_LEN + s) * HD;
      dst[lane]      = f2b(q0 * scale);
      dst[lane + 64] = f2b(q1 * scale);
    } else {                      // V head r-40: quant-dequant only
      int h = r - 40;
      const unsigned short* src = qkv + (long)s * QKV_N + 5120 + h * HD;
      float x0 = b2f(src[lane]), x1 = b2f(src[lane + 64]);
      float m = fmaxf(fabsf(x0), fabsf(x1));
      for (int off = 32; off; off >>= 1) m = fmaxf(m, __shfl_xor(m, off, 64));
      float scale = fmaxf(m / 127.0f, 1e-9f);
      float q0 = fminf(fmaxf(rintf(x0 / scale), -128.f), 127.f);
      float q1 = fminf(fmaxf(rintf(x1 / scale), -128.f), 127.f);
      unsigned short* dst = Vb + ((long)h * S_LEN + s) * HD;
      dst[lane]      = f2b(q0 * scale);
      dst[lane + 64] = f2b(q1 * scale);
    }
  }
}

// -------------------------------------------------- V transpose: [h][s][d]->[h][d][s]
__global__ __launch_bounds__(256) void transpose_v(const unsigned short* __restrict__ Vb,
                                                   unsigned short* __restrict__ Vtb) {
  __shared__ unsigned short t[64][136];
  const int h = blockIdx.x >> 5, st = blockIdx.x & 31;
  const int tid = threadIdx.x;
  const long vbase = (long)h * S_LEN * HD;
#pragma unroll
  for (int p = 0; p < 8; ++p) {
    int e = p * 1024 + tid * 4;
    int sl = e >> 7, d = e & 127;
    ushort4 v = *(const ushort4*)(Vb + vbase + (long)(st * 64 + sl) * HD + d);
    t[sl][d] = v.x; t[sl][d + 1] = v.y; t[sl][d + 2] = v.z; t[sl][d + 3] = v.w;
  }
  __syncthreads();
  const long tbase = (long)h * HD * S_LEN;
#pragma unroll
  for (int p = 0; p < 8; ++p) {
    int o = p * 1024 + tid * 4;
    int d = o >> 6, sl = o & 63;
    ushort4 v;
    v.x = t[sl][d]; v.y = t[sl + 1][d]; v.z = t[sl + 2][d]; v.w = t[sl + 3][d];
    *(ushort4*)(Vtb + tbase + (long)d * S_LEN + st * 64 + sl) = v;
  }
}

// ------------------------------------------------------------- flash attention
// block = (head, 128-row q-tile). 4 waves x 32 q-rows. K/V tiles 128x128 in LDS
// with XOR swizzle (16B-block b stored at b^(row&15)) so global_load_lds's
// contiguous write pattern stays legal while frag reads stay ~conflict-free.
// P reuses the K buffer (K dead after S) -> 64KB LDS -> 2 blocks/CU.
__global__ __launch_bounds__(256, 2) void attn_kernel(const unsigned short* __restrict__ Qb,
                                                      const unsigned short* __restrict__ Kb,
                                                      const unsigned short* __restrict__ Vtb,
                                                      unsigned short* __restrict__ Ob) {
  __shared__ __align__(16) unsigned short KPs[128 * 128];  // K tile, then P
  __shared__ __align__(16) unsigned short Vs[128 * 128];   // Vt tile [d][key]

  const int bx = blockIdx.x;
  const int i = bx >> 5;
  const int qt = (i < 8) ? (15 - i) : (i - 8);  // pair heavy+light per CU
  const int h = bx & 31;
  const int hk = h >> 2;                        // GQA: 4 q-heads per kv-head
  const int tid = threadIdx.x;
  const int lane = tid & 63, wave = tid >> 6;
  const int quad = lane >> 4, l16 = lane & 15;

  // Q fragments for this wave's 32 rows (A-operand layout), from global
  bf16x8 qf[2][4];
  {
    const unsigned short* qb =
        Qb + ((long)h * S_LEN + qt * 128 + wave * 32 + l16) * HD + quad * 8;
#pragma unroll
    for (int mi = 0; mi < 2; ++mi)
#pragma unroll
      for (int ks = 0; ks < 4; ++ks)
        qf[mi][ks] = *(const bf16x8*)(qb + mi * 16 * HD + ks * 32);
  }

  f32x4 O[2][8] = {};
  float mrow[2][4], lrow[2][4];
#pragma unroll
  for (int mi = 0; mi < 2; ++mi)
#pragma unroll
    for (int r = 0; r < 4; ++r) { mrow[mi][r] = -1e30f; lrow[mi][r] = 0.f; }

  const unsigned short* Kbase = Kb + (long)hk * S_LEN * HD;
  const unsigned short* Vbase = Vtb + (long)hk * HD * S_LEN;
  const float sscale = 0.08838834764831845f;  // 1/sqrt(128)

  for (int kt = 0; kt <= qt; ++kt) {
    __syncthreads();  // previous iter's LDS reads done
#pragma unroll
    for (int c = 0; c < 8; ++c) {
      int p = c * 256 + tid;          // 16B-block position in LDS
      int row = p >> 4, bp = p & 15;
      int gcol = (bp ^ (row & 15)) * 8;
      gl_lds16(Kbase + (long)(kt * 128 + row) * HD + gcol, KPs + c * 2048 + wave * 512);
      gl_lds16(Vbase + (long)row * S_LEN + kt * 128 + gcol, Vs + c * 2048 + wave * 512);
    }
    __syncthreads();

    // S = Q K^T
    f32x4 S[2][8] = {};
#pragma unroll
    for (int ks = 0; ks < 4; ++ks) {
#pragma unroll
      for (int ni = 0; ni < 8; ++ni) {
        int rk = ni * 16 + l16;
        int blk = (ks * 4 + quad) ^ (rk & 15);
        bf16x8 kf = *(const bf16x8*)&KPs[rk * 128 + blk * 8];
        S[0][ni] = __builtin_amdgcn_mfma_f32_16x16x32_bf16(qf[0][ks], kf, S[0][ni], 0, 0, 0);
        S[1][ni] = __builtin_amdgcn_mfma_f32_16x16x32_bf16(qf[1][ks], kf, S[1][ni], 0, 0, 0);
      }
    }

    // scale + causal mask + row max
    const bool diag = (kt == qt);
    const int qrow_base = qt * 128 + wave * 32;
    float rmax[2][4];
#pragma unroll
    for (int mi = 0; mi < 2; ++mi)
#pragma unroll
      for (int r = 0; r < 4; ++r) rmax[mi][r] = -1e30f;
#pragma unroll
    for (int mi = 0; mi < 2; ++mi)
#pragma unroll
      for (int ni = 0; ni < 8; ++ni) {
        int col = kt * 128 + ni * 16 + l16;
#pragma unroll
        for (int r = 0; r < 4; ++r) {
          int row = qrow_base + mi * 16 + quad * 4 + r;
          float v = S[mi][ni][r] * sscale;
          if (diag && col > row) v = -1e9f;
          S[mi][ni][r] = v;
          rmax[mi][r] = fmaxf(rmax[mi][r], v);
        }
      }
    float alpha[2][4], rsum[2][4];
#pragma unroll
    for (int mi = 0; mi < 2; ++mi)
#pragma unroll
      for (int r = 0; r < 4; ++r) {
        float v = rmax[mi][r];
        v = fmaxf(v, __shfl_xor(v, 1, 64));
        v = fmaxf(v, __shfl_xor(v, 2, 64));
        v = fmaxf(v, __shfl_xor(v, 4, 64));
        v = fmaxf(v, __shfl_xor(v, 8, 64));
        float mnew = fmaxf(mrow[mi][r], v);
        alpha[mi][r] = __expf(mrow[mi][r] - mnew);
        mrow[mi][r] = mnew;
        rsum[mi][r] = 0.f;
      }

    __syncthreads();  // all waves done reading K tile; reuse buffer for P

    // P = exp(S - m), bf16 into KPs (same XOR swizzle), accumulate row sums
#pragma unroll
    for (int mi = 0; mi < 2; ++mi)
#pragma unroll
      for (int ni = 0; ni < 8; ++ni)
#pragma unroll
        for (int r = 0; r < 4; ++r) {
          float p = __expf(S[mi][ni][r] - mrow[mi][r]);
          rsum[mi][r] += p;
          int prow = wave * 32 + mi * 16 + quad * 4 + r;
          int pcol = ni * 16 + l16;
          int pb = (pcol >> 3) ^ (prow & 15);
          KPs[prow * 128 + pb * 8 + (pcol & 7)] = f2b(p);
        }
#pragma unroll
    for (int mi = 0; mi < 2; ++mi)
#pragma unroll
      for (int r = 0; r < 4; ++r) {
        float v = rsum[mi][r];
        v += __shfl_xor(v, 1, 64);
        v += __shfl_xor(v, 2, 64);
        v += __shfl_xor(v, 4, 64);
        v += __shfl_xor(v, 8, 64);
        lrow[mi][r] = lrow[mi][r] * alpha[mi][r] + v;
      }
#pragma unroll
    for (int mi = 0; mi < 2; ++mi)
#pragma unroll
      for (int ni = 0; ni < 8; ++ni)
#pragma unroll
        for (int r = 0; r < 4; ++r) O[mi][ni][r] *= alpha[mi][r];

    __syncthreads();  // P writes visible (wave-local, but barrier is safest)

    // O += P V
#pragma unroll
    for (int ks2 = 0; ks2 < 4; ++ks2) {
      bf16x8 pf[2];
#pragma unroll
      for (int mi = 0; mi < 2; ++mi) {
        int prow = wave * 32 + mi * 16 + l16;
        int pb = (ks2 * 4 + quad) ^ (prow & 15);
        pf[mi] = *(const bf16x8*)&KPs[prow * 128 + pb * 8];
      }
#pragma unroll
      for (int ni = 0; ni < 8; ++ni) {
        int rv = ni * 16 + l16;
        int blk = (ks2 * 4 + quad) ^ (rv & 15);
        bf16x8 vf = *(const bf16x8*)&Vs[rv * 128 + blk * 8];
        O[0][ni] = __builtin_amdgcn_mfma_f32_16x16x32_bf16(pf[0], vf, O[0][ni], 0, 0, 0);
        O[1][ni] = __builtin_amdgcn_mfma_f32_16x16x32_bf16(pf[1], vf, O[1][ni], 0, 0, 0);
      }
    }
  }

  // normalize + store bf16 at [s][h*128+d]
#pragma unroll
  for (int mi = 0; mi < 2; ++mi)
#pragma unroll
    for (int r = 0; r < 4; ++r) {
      float inv = 1.0f / lrow[mi][r];
      long srow = qt * 128 + wave * 32 + mi * 16 + quad * 4 + r;
#pragma unroll
      for (int ni = 0; ni < 8; ++ni) {
        long col = (long)h * HD + ni * 16 + l16;
        Ob[srow * (long)HID + col] = f2b(O[mi][ni][r] * inv);
      }
    }
}

// ---------------------------------------------------------------------------
extern "C" void kernel_launch(void* const* d_in, const int* in_sizes, int n_in,
                              void* d_out, int out_size, void* d_ws, size_t ws_size,
                              hipStream_t stream) {
  const float* hidden = (const float*)d_in[0];
  const float* wq = (const float*)d_in[1];
  const float* wk = (const float*)d_in[2];
  const float* wv = (const float*)d_in[3];
  const float* wo = (const float*)d_in[4];
  const int* pos = (const int*)d_in[5];
  float* out = (float*)d_out;

  // workspace layout (bytes); total 138,412,032. Overlays: Qb=hid_b (hid dead
  // after GEMM1), attn_b=qkv_b (qkv dead after postproc).
  char* ws = (char*)d_ws;
  unsigned short* wqkv_b = (unsigned short*)(ws);               // 50,331,648
  unsigned short* wo_b   = (unsigned short*)(ws + 50331648);    // 33,554,432
  unsigned short* hid_b  = (unsigned short*)(ws + 83886080);    // 16,777,216
  unsigned short* qkv_b  = (unsigned short*)(ws + 100663296);   // 25,165,824
  unsigned short* Kb     = (unsigned short*)(ws + 125829120);   //  4,194,304
  unsigned short* Vb     = (unsigned short*)(ws + 130023424);   //  4,194,304
  unsigned short* Vtb    = (unsigned short*)(ws + 134217728);   //  4,194,304
  unsigned short* Qb     = hid_b;
  unsigned short* attn_b = qkv_b;

  cast_kernel<<<8388608 / 1024, 256, 0, stream>>>(hidden, hid_b, 8388608 / 4);
  cast_kernel<<<16777216 / 1024, 256, 0, stream>>>(wq, wqkv_b, 16777216 / 4);
  cast_kernel<<<4194304 / 1024, 256, 0, stream>>>(wk, wqkv_b + 16777216, 4194304 / 4);
  cast_kernel<<<4194304 / 1024, 256, 0, stream>>>(wv, wqkv_b + 20971520, 4194304 / 4);
  cast_kernel<<<16777216 / 1024, 256, 0, stream>>>(wo, wo_b, 16777216 / 4);

  gemm_bt<1><<<dim3(QKV_N / 128, S_LEN / 128), 256, 0, stream>>>(
      hid_b, wqkv_b, (void*)qkv_b, S_LEN, QKV_N, HID);

  postproc<<<S_LEN, 256, 0, stream>>>(qkv_b, pos, Qb, Kb, Vb);
  transpose_v<<<NKV * 32, 256, 0, stream>>>(Vb, Vtb);
  attn_kernel<<<NH * 16, 256, 0, stream>>>(Qb, Kb, Vtb, attn_b);

  gemm_bt<0><<<dim3(HID / 128, S_LEN / 128), 256, 0, stream>>>(
      attn_b, wo_b, (void*)out, S_LEN, HID, HID);
}

// Round 2
// 734.473 us; speedup vs baseline: 1.0026x; 1.0026x over previous
//
#include <hip/hip_runtime.h>

// ---------------------------------------------------------------------------
// LlamaAttention_Tender: hidden(2048x4096) -> QKV proj -> RoPE -> int8 qdq(K,V)
// -> GQA causal attention (32 q-heads, 8 kv-heads, D=128) -> out proj.
// All matmuls via bf16 16x16x32 MFMA, fp32 accum. fp32 inputs cast to bf16.
// R1: attn kernel XCD-swizzled so kv_head == blockIdx%8 == XCD -> K/V (1MB)
//     L2-resident per XCD; removed wave-local P barrier.
// ---------------------------------------------------------------------------

#define S_LEN 2048
#define HID 4096
#define NH 32
#define NKV 8
#define HD 128
#define QKV_N 6144   // 4096 q + 1024 k + 1024 v

typedef __bf16 bf16x8 __attribute__((ext_vector_type(8)));
typedef float f32x4 __attribute__((ext_vector_type(4)));

__device__ __forceinline__ unsigned short f2b(float f) {
  unsigned int u = __float_as_uint(f);
  u += 0x7fffu + ((u >> 16) & 1u);   // round-to-nearest-even
  return (unsigned short)(u >> 16);
}
__device__ __forceinline__ float b2f(unsigned short h) {
  return __uint_as_float(((unsigned int)h) << 16);
}
// async global->LDS, 16B per lane. LDS dst must be wave-uniform (lane*16 implicit).
__device__ __forceinline__ void gl_lds16(const void* g, void* l) {
  __builtin_amdgcn_global_load_lds(
      (__attribute__((address_space(1))) void*)g,
      (__attribute__((address_space(3))) void*)l, 16, 0, 0);
}

// ---------------------------------------------------------------- cast fp32->bf16
__global__ __launch_bounds__(256) void cast_kernel(const float* __restrict__ src,
                                                   unsigned short* __restrict__ dst,
                                                   int n4) {
  int i = blockIdx.x * 256 + threadIdx.x;
  if (i >= n4) return;
  float4 v = ((const float4*)src)[i];
  ushort4 o;
  o.x = f2b(v.x); o.y = f2b(v.y); o.z = f2b(v.z); o.w = f2b(v.w);
  ((ushort4*)dst)[i] = o;
}

// ------------------------------------------------------- B^T GEMM (m97 structure)
// C[M,N] = A[M,K] * B[N,K]^T, 128x128 tile, BK=32, 256 thr (4 waves, 64x64 each).
template <int OUT_BF16>
__global__ __launch_bounds__(256) void gemm_bt(const unsigned short* __restrict__ A,
                                               const unsigned short* __restrict__ B,
                                               void* __restrict__ Cout,
                                               int M, int N, int K) {
  __shared__ __align__(16) unsigned short As[128 * 32];
  __shared__ __align__(16) unsigned short Bs[128 * 32];
  const int tid = threadIdx.x;
  const int lane = tid & 63, wave = tid >> 6;
  const int quad = lane >> 4, l16 = lane & 15;
  const long row0 = (long)blockIdx.y * 128;
  const long col0 = (long)blockIdx.x * 128;
  const int wr = (wave >> 1) * 64, wc = (wave & 1) * 64;

  f32x4 acc[4][4] = {};

  // staging map: call c covers flat elems [c*2048, c*2048+2048), 8 elems/lane
  const int e0 = tid * 8;
  const int r0s = e0 >> 5, c0s = e0 & 31;
  const int r1s = (e0 + 2048) >> 5;  // c1s == c0s
  const unsigned short* Ap0 = A + (row0 + r0s) * (long)K + c0s;
  const unsigned short* Ap1 = A + (row0 + r1s) * (long)K + c0s;
  const unsigned short* Bp0 = B + (col0 + r0s) * (long)K + c0s;
  const unsigned short* Bp1 = B + (col0 + r1s) * (long)K + c0s;
  unsigned short* AsD0 = As + wave * 512;
  unsigned short* AsD1 = As + 2048 + wave * 512;
  unsigned short* BsD0 = Bs + wave * 512;
  unsigned short* BsD1 = Bs + 2048 + wave * 512;

  for (int k0 = 0; k0 < K; k0 += 32) {
    __syncthreads();
    gl_lds16(Ap0 + k0, AsD0);
    gl_lds16(Ap1 + k0, AsD1);
    gl_lds16(Bp0 + k0, BsD0);
    gl_lds16(Bp1 + k0, BsD1);
    __syncthreads();
    bf16x8 af[4], bf[4];
#pragma unroll
    for (int mi = 0; mi < 4; ++mi)
      af[mi] = *(const bf16x8*)&As[(wr + mi * 16 + l16) * 32 + quad * 8];
#pragma unroll
    for (int ni = 0; ni < 4; ++ni)
      bf[ni] = *(const bf16x8*)&Bs[(wc + ni * 16 + l16) * 32 + quad * 8];
#pragma unroll
    for (int mi = 0; mi < 4; ++mi)
#pragma unroll
      for (int ni = 0; ni < 4; ++ni)
        acc[mi][ni] = __builtin_amdgcn_mfma_f32_16x16x32_bf16(af[mi], bf[ni], acc[mi][ni], 0, 0, 0);
  }
#pragma unroll
  for (int mi = 0; mi < 4; ++mi)
#pragma unroll
    for (int ni = 0; ni < 4; ++ni)
#pragma unroll
      for (int r = 0; r < 4; ++r) {
        long row = row0 + wr + mi * 16 + quad * 4 + r;
        long col = col0 + wc + ni * 16 + l16;
        float v = acc[mi][ni][r];
        if (OUT_BF16) ((unsigned short*)Cout)[row * N + col] = f2b(v);
        else          ((float*)Cout)[row * N + col] = v;
      }
}

// ------------------------------------------- RoPE + sym int8 quant-dequant + split
// qkv[2048][6144] bf16 -> Qb[32][2048][128], Kb[8][2048][128], Vb[8][2048][128]
__global__ __launch_bounds__(256) void postproc(const unsigned short* __restrict__ qkv,
                                                const int* __restrict__ pos_ids,
                                                unsigned short* __restrict__ Qb,
                                                unsigned short* __restrict__ Kb,
                                                unsigned short* __restrict__ Vb) {
  const int s = blockIdx.x;
  const int lane = threadIdx.x & 63, wave = threadIdx.x >> 6;
  const float pos = (float)pos_ids[s];
  // inv_freq = 10000^(-lane/64) = exp(-lane * ln(10000)/64); pair (d, d+64)
  const float invf = expf(-(float)lane * 0.14391156831212787f);
  const float ang = pos * invf;
  const float ca = cosf(ang), sa = sinf(ang);

  for (int r = wave; r < 48; r += 4) {
    if (r < 32) {                 // Q head r: rope only
      const unsigned short* src = qkv + (long)s * QKV_N + r * HD;
      float x0 = b2f(src[lane]), x1 = b2f(src[lane + 64]);
      unsigned short* dst = Qb + ((long)r * S_LEN + s) * HD;
      dst[lane]      = f2b(x0 * ca - x1 * sa);
      dst[lane + 64] = f2b(x1 * ca + x0 * sa);
    } else if (r < 40) {          // K head r-32: rope then quant-dequant
      int h = r - 32;
      const unsigned short* src = qkv + (long)s * QKV_N + 4096 + h * HD;
      float x0 = b2f(src[lane]), x1 = b2f(src[lane + 64]);
      float y0 = x0 * ca - x1 * sa;
      float y1 = x1 * ca + x0 * sa;
      float m = fmaxf(fabsf(y0), fabsf(y1));
      for (int off = 32; off; off >>= 1) m = fmaxf(m, __shfl_xor(m, off, 64));
      float scale = fmaxf(m / 127.0f, 1e-9f);
      float q0 = fminf(fmaxf(rintf(y0 / scale), -128.f), 127.f);
      float q1 = fminf(fmaxf(rintf(y1 / scale), -128.f), 127.f);
      unsigned short* dst = Kb + ((long)h * S_LEN + s) * HD;
      dst[lane]      = f2b(q0 * scale);
      dst[lane + 64] = f2b(q1 * scale);
    } else {                      // V head r-40: quant-dequant only
      int h = r - 40;
      const unsigned short* src = qkv + (long)s * QKV_N + 5120 + h * HD;
      float x0 = b2f(src[lane]), x1 = b2f(src[lane + 64]);
      float m = fmaxf(fabsf(x0), fabsf(x1));
      for (int off = 32; off; off >>= 1) m = fmaxf(m, __shfl_xor(m, off, 64));
      float scale = fmaxf(m / 127.0f, 1e-9f);
      float q0 = fminf(fmaxf(rintf(x0 / scale), -128.f), 127.f);
      float q1 = fminf(fmaxf(rintf(x1 / scale), -128.f), 127.f);
      unsigned short* dst = Vb + ((long)h * S_LEN + s) * HD;
      dst[lane]      = f2b(q0 * scale);
      dst[lane + 64] = f2b(q1 * scale);
    }
  }
}

// -------------------------------------------------- V transpose: [h][s][d]->[h][d][s]
__global__ __launch_bounds__(256) void transpose_v(const unsigned short* __restrict__ Vb,
                                                   unsigned short* __restrict__ Vtb) {
  __shared__ unsigned short t[64][136];
  const int h = blockIdx.x >> 5, st = blockIdx.x & 31;
  const int tid = threadIdx.x;
  const long vbase = (long)h * S_LEN * HD;
#pragma unroll
  for (int p = 0; p < 8; ++p) {
    int e = p * 1024 + tid * 4;
    int sl = e >> 7, d = e & 127;
    ushort4 v = *(const ushort4*)(Vb + vbase + (long)(st * 64 + sl) * HD + d);
    t[sl][d] = v.x; t[sl][d + 1] = v.y; t[sl][d + 2] = v.z; t[sl][d + 3] = v.w;
  }
  __syncthreads();
  const long tbase = (long)h * HD * S_LEN;
#pragma unroll
  for (int p = 0; p < 8; ++p) {
    int o = p * 1024 + tid * 4;
    int d = o >> 6, sl = o & 63;
    ushort4 v;
    v.x = t[sl][d]; v.y = t[sl + 1][d]; v.z = t[sl + 2][d]; v.w = t[sl + 3][d];
    *(ushort4*)(Vtb + tbase + (long)d * S_LEN + st * 64 + sl) = v;
  }
}

// ------------------------------------------------------------- flash attention
// block = (head, 128-row q-tile). 4 waves x 32 q-rows. K/V tiles 128x128 in LDS
// with XOR swizzle (16B-block b stored at b^(row&15)) so global_load_lds's
// contiguous write pattern stays legal while frag reads stay ~conflict-free.
// P reuses the K buffer (K dead after S) -> 64KB LDS -> 2 blocks/CU.
// XCD locality: kv_head = blockIdx%8 == XCD id -> each XCD's L2 holds exactly
// one kv-head's K+V (1MB), reused by all 64 blocks of that kv-head.
__global__ __launch_bounds__(256, 2) void attn_kernel(const unsigned short* __restrict__ Qb,
                                                      const unsigned short* __restrict__ Kb,
                                                      const unsigned short* __restrict__ Vtb,
                                                      unsigned short* __restrict__ Ob) {
  __shared__ __align__(16) unsigned short KPs[128 * 128];  // K tile, then P
  __shared__ __align__(16) unsigned short Vs[128 * 128];   // Vt tile [d][key]

  const int bx = blockIdx.x;
  const int hk = bx & 7;          // kv-head == XCD (blockIdx % 8 -> XCD)
  const int j = bx >> 3;          // 0..63 within XCD
  const int qh = j & 3;           // q-head within GQA group
  const int i = j >> 2;           // 0..15
  const int qt = (i < 8) ? (15 - i) : (i - 8);  // pair heavy+light per CU
  const int h = hk * 4 + qh;
  const int tid = threadIdx.x;
  const int lane = tid & 63, wave = tid >> 6;
  const int quad = lane >> 4, l16 = lane & 15;

  // Q fragments for this wave's 32 rows (A-operand layout), from global
  bf16x8 qf[2][4];
  {
    const unsigned short* qb =
        Qb + ((long)h * S_LEN + qt * 128 + wave * 32 + l16) * HD + quad * 8;
#pragma unroll
    for (int mi = 0; mi < 2; ++mi)
#pragma unroll
      for (int ks = 0; ks < 4; ++ks)
        qf[mi][ks] = *(const bf16x8*)(qb + mi * 16 * HD + ks * 32);
  }

  f32x4 O[2][8] = {};
  float mrow[2][4], lrow[2][4];
#pragma unroll
  for (int mi = 0; mi < 2; ++mi)
#pragma unroll
    for (int r = 0; r < 4; ++r) { mrow[mi][r] = -1e30f; lrow[mi][r] = 0.f; }

  const unsigned short* Kbase = Kb + (long)hk * S_LEN * HD;
  const unsigned short* Vbase = Vtb + (long)hk * HD * S_LEN;
  const float sscale = 0.08838834764831845f;  // 1/sqrt(128)

  for (int kt = 0; kt <= qt; ++kt) {
    __syncthreads();  // previous iter's LDS reads done
#pragma unroll
    for (int c = 0; c < 8; ++c) {
      int p = c * 256 + tid;          // 16B-block position in LDS
      int row = p >> 4, bp = p & 15;
      int gcol = (bp ^ (row & 15)) * 8;
      gl_lds16(Kbase + (long)(kt * 128 + row) * HD + gcol, KPs + c * 2048 + wave * 512);
      gl_lds16(Vbase + (long)row * S_LEN + kt * 128 + gcol, Vs + c * 2048 + wave * 512);
    }
    __syncthreads();

    // S = Q K^T
    f32x4 S[2][8] = {};
#pragma unroll
    for (int ks = 0; ks < 4; ++ks) {
#pragma unroll
      for (int ni = 0; ni < 8; ++ni) {
        int rk = ni * 16 + l16;
        int blk = (ks * 4 + quad) ^ (rk & 15);
        bf16x8 kf = *(const bf16x8*)&KPs[rk * 128 + blk * 8];
        S[0][ni] = __builtin_amdgcn_mfma_f32_16x16x32_bf16(qf[0][ks], kf, S[0][ni], 0, 0, 0);
        S[1][ni] = __builtin_amdgcn_mfma_f32_16x16x32_bf16(qf[1][ks], kf, S[1][ni], 0, 0, 0);
      }
    }

    // scale + causal mask + row max
    const bool diag = (kt == qt);
    const int qrow_base = qt * 128 + wave * 32;
    float rmax[2][4];
#pragma unroll
    for (int mi = 0; mi < 2; ++mi)
#pragma unroll
      for (int r = 0; r < 4; ++r) rmax[mi][r] = -1e30f;
#pragma unroll
    for (int mi = 0; mi < 2; ++mi)
#pragma unroll
      for (int ni = 0; ni < 8; ++ni) {
        int col = kt * 128 + ni * 16 + l16;
#pragma unroll
        for (int r = 0; r < 4; ++r) {
          int row = qrow_base + mi * 16 + quad * 4 + r;
          float v = S[mi][ni][r] * sscale;
          if (diag && col > row) v = -1e9f;
          S[mi][ni][r] = v;
          rmax[mi][r] = fmaxf(rmax[mi][r], v);
        }
      }
    float alpha[2][4], rsum[2][4];
#pragma unroll
    for (int mi = 0; mi < 2; ++mi)
#pragma unroll
      for (int r = 0; r < 4; ++r) {
        float v = rmax[mi][r];
        v = fmaxf(v, __shfl_xor(v, 1, 64));
        v = fmaxf(v, __shfl_xor(v, 2, 64));
        v = fmaxf(v, __shfl_xor(v, 4, 64));
        v = fmaxf(v, __shfl_xor(v, 8, 64));
        float mnew = fmaxf(mrow[mi][r], v);
        alpha[mi][r] = __expf(mrow[mi][r] - mnew);
        mrow[mi][r] = mnew;
        rsum[mi][r] = 0.f;
      }

    __syncthreads();  // all waves done reading K tile; reuse buffer for P

    // P = exp(S - m), bf16 into KPs (same XOR swizzle), accumulate row sums.
    // P rows written/read by the SAME wave -> no barrier needed before PV.
#pragma unroll
    for (int mi = 0; mi < 2; ++mi)
#pragma unroll
      for (int ni = 0; ni < 8; ++ni)
#pragma unroll
        for (int r = 0; r < 4; ++r) {
          float p = __expf(S[mi][ni][r] - mrow[mi][r]);
          rsum[mi][r] += p;
          int prow = wave * 32 + mi * 16 + quad * 4 + r;
          int pcol = ni * 16 + l16;
          int pb = (pcol >> 3) ^ (prow & 15);
          KPs[prow * 128 + pb * 8 + (pcol & 7)] = f2b(p);
        }
#pragma unroll
    for (int mi = 0; mi < 2; ++mi)
#pragma unroll
      for (int r = 0; r < 4; ++r) {
        float v = rsum[mi][r];
        v += __shfl_xor(v, 1, 64);
        v += __shfl_xor(v, 2, 64);
        v += __shfl_xor(v, 4, 64);
        v += __shfl_xor(v, 8, 64);
        lrow[mi][r] = lrow[mi][r] * alpha[mi][r] + v;
      }
#pragma unroll
    for (int mi = 0; mi < 2; ++mi)
#pragma unroll
      for (int ni = 0; ni < 8; ++ni)
#pragma unroll
        for (int r = 0; r < 4; ++r) O[mi][ni][r] *= alpha[mi][r];

    // O += P V
#pragma unroll
    for (int ks2 = 0; ks2 < 4; ++ks2) {
      bf16x8 pf[2];
#pragma unroll
      for (int mi = 0; mi < 2; ++mi) {
        int prow = wave * 32 + mi * 16 + l16;
        int pb = (ks2 * 4 + quad) ^ (prow & 15);
        pf[mi] = *(const bf16x8*)&KPs[prow * 128 + pb * 8];
      }
#pragma unroll
      for (int ni = 0; ni < 8; ++ni) {
        int rv = ni * 16 + l16;
        int blk = (ks2 * 4 + quad) ^ (rv & 15);
        bf16x8 vf = *(const bf16x8*)&Vs[rv * 128 + blk * 8];
        O[0][ni] = __builtin_amdgcn_mfma_f32_16x16x32_bf16(pf[0], vf, O[0][ni], 0, 0, 0);
        O[1][ni] = __builtin_amdgcn_mfma_f32_16x16x32_bf16(pf[1], vf, O[1][ni], 0, 0, 0);
      }
    }
  }

  // normalize + store bf16 at [s][h*128+d]
#pragma unroll
  for (int mi = 0; mi < 2; ++mi)
#pragma unroll
    for (int r = 0; r < 4; ++r) {
      float inv = 1.0f / lrow[mi][r];
      long srow = qt * 128 + wave * 32 + mi * 16 + quad * 4 + r;
#pragma unroll
      for (int ni = 0; ni < 8; ++ni) {
        long col = (long)h * HD + ni * 16 + l16;
        Ob[srow * (long)HID + col] = f2b(O[mi][ni][r] * inv);
      }
    }
}

// ---------------------------------------------------------------------------
extern "C" void kernel_launch(void* const* d_in, const int* in_sizes, int n_in,
                              void* d_out, int out_size, void* d_ws, size_t ws_size,
                              hipStream_t stream) {
  const float* hidden = (const float*)d_in[0];
  const float* wq = (const float*)d_in[1];
  const float* wk = (const float*)d_in[2];
  const float* wv = (const float*)d_in[3];
  const float* wo = (const float*)d_in[4];
  const int* pos = (const int*)d_in[5];
  float* out = (float*)d_out;

  // workspace layout (bytes); total 138,412,032. Overlays: Qb=hid_b (hid dead
  // after GEMM1), attn_b=qkv_b (qkv dead after postproc).
  char* ws = (char*)d_ws;
  unsigned short* wqkv_b = (unsigned short*)(ws);               // 50,331,648
  unsigned short* wo_b   = (unsigned short*)(ws + 50331648);    // 33,554,432
  unsigned short* hid_b  = (unsigned short*)(ws + 83886080);    // 16,777,216
  unsigned short* qkv_b  = (unsigned short*)(ws + 100663296);   // 25,165,824
  unsigned short* Kb     = (unsigned short*)(ws + 125829120);   //  4,194,304
  unsigned short* Vb     = (unsigned short*)(ws + 130023424);   //  4,194,304
  unsigned short* Vtb    = (unsigned short*)(ws + 134217728);   //  4,194,304
  unsigned short* Qb     = hid_b;
  unsigned short* attn_b = qkv_b;

  cast_kernel<<<8388608 / 1024, 256, 0, stream>>>(hidden, hid_b, 8388608 / 4);
  cast_kernel<<<16777216 / 1024, 256, 0, stream>>>(wq, wqkv_b, 16777216 / 4);
  cast_kernel<<<4194304 / 1024, 256, 0, stream>>>(wk, wqkv_b + 16777216, 4194304 / 4);
  cast_kernel<<<4194304 / 1024, 256, 0, stream>>>(wv, wqkv_b + 20971520, 4194304 / 4);
  cast_kernel<<<16777216 / 1024, 256, 0, stream>>>(wo, wo_b, 16777216 / 4);

  gemm_bt<1><<<dim3(QKV_N / 128, S_LEN / 128), 256, 0, stream>>>(
      hid_b, wqkv_b, (void*)qkv_b, S_LEN, QKV_N, HID);

  postproc<<<S_LEN, 256, 0, stream>>>(qkv_b, pos, Qb, Kb, Vb);
  transpose_v<<<NKV * 32, 256, 0, stream>>>(Vb, Vtb);
  attn_kernel<<<NH * 16, 256, 0, stream>>>(Qb, Kb, Vtb, attn_b);

  gemm_bt<0><<<dim3(HID / 128, S_LEN / 128), 256, 0, stream>>>(
      attn_b, wo_b, (void*)out, S_LEN, HID, HID);
}

// Round 3
// 631.938 us; speedup vs baseline: 1.1652x; 1.1623x over previous
//
#include <hip/hip_runtime.h>

// ---------------------------------------------------------------------------
// LlamaAttention_Tender: hidden(2048x4096) -> QKV proj -> RoPE -> int8 qdq(K,V)
// -> GQA causal attention (32 q-heads, 8 kv-heads, D=128) -> out proj.
// All matmuls via bf16 16x16x32 MFMA, fp32 accum. fp32 inputs cast to bf16.
// R2: attention rewritten BARRIER-FREE: K/Vt fragments loaded directly
//     global->VGPR (no LDS staging, no __syncthreads, no vmcnt(0) drain);
//     P round-trips through wave-local LDS only. Equal-work complementary
//     qt pairing robust to either {2c,2c+1} or {c,c+256} CU co-residency.
// ---------------------------------------------------------------------------

#define S_LEN 2048
#define HID 4096
#define NH 32
#define NKV 8
#define HD 128
#define QKV_N 6144   // 4096 q + 1024 k + 1024 v

typedef __bf16 bf16x8 __attribute__((ext_vector_type(8)));
typedef float f32x4 __attribute__((ext_vector_type(4)));

__device__ __forceinline__ unsigned short f2b(float f) {
  unsigned int u = __float_as_uint(f);
  u += 0x7fffu + ((u >> 16) & 1u);   // round-to-nearest-even
  return (unsigned short)(u >> 16);
}
__device__ __forceinline__ float b2f(unsigned short h) {
  return __uint_as_float(((unsigned int)h) << 16);
}
// async global->LDS, 16B per lane. LDS dst must be wave-uniform (lane*16 implicit).
__device__ __forceinline__ void gl_lds16(const void* g, void* l) {
  __builtin_amdgcn_global_load_lds(
      (__attribute__((address_space(1))) void*)g,
      (__attribute__((address_space(3))) void*)l, 16, 0, 0);
}

// ---------------------------------------------------------------- cast fp32->bf16
__global__ __launch_bounds__(256) void cast_kernel(const float* __restrict__ src,
                                                   unsigned short* __restrict__ dst,
                                                   int n4) {
  int i = blockIdx.x * 256 + threadIdx.x;
  if (i >= n4) return;
  float4 v = ((const float4*)src)[i];
  ushort4 o;
  o.x = f2b(v.x); o.y = f2b(v.y); o.z = f2b(v.z); o.w = f2b(v.w);
  ((ushort4*)dst)[i] = o;
}

// ------------------------------------------------------- B^T GEMM (m97 structure)
// C[M,N] = A[M,K] * B[N,K]^T, 128x128 tile, BK=32, 256 thr (4 waves, 64x64 each).
template <int OUT_BF16>
__global__ __launch_bounds__(256) void gemm_bt(const unsigned short* __restrict__ A,
                                               const unsigned short* __restrict__ B,
                                               void* __restrict__ Cout,
                                               int M, int N, int K) {
  __shared__ __align__(16) unsigned short As[128 * 32];
  __shared__ __align__(16) unsigned short Bs[128 * 32];
  const int tid = threadIdx.x;
  const int lane = tid & 63, wave = tid >> 6;
  const int quad = lane >> 4, l16 = lane & 15;
  const long row0 = (long)blockIdx.y * 128;
  const long col0 = (long)blockIdx.x * 128;
  const int wr = (wave >> 1) * 64, wc = (wave & 1) * 64;

  f32x4 acc[4][4] = {};

  // staging map: call c covers flat elems [c*2048, c*2048+2048), 8 elems/lane
  const int e0 = tid * 8;
  const int r0s = e0 >> 5, c0s = e0 & 31;
  const int r1s = (e0 + 2048) >> 5;  // c1s == c0s
  const unsigned short* Ap0 = A + (row0 + r0s) * (long)K + c0s;
  const unsigned short* Ap1 = A + (row0 + r1s) * (long)K + c0s;
  const unsigned short* Bp0 = B + (col0 + r0s) * (long)K + c0s;
  const unsigned short* Bp1 = B + (col0 + r1s) * (long)K + c0s;
  unsigned short* AsD0 = As + wave * 512;
  unsigned short* AsD1 = As + 2048 + wave * 512;
  unsigned short* BsD0 = Bs + wave * 512;
  unsigned short* BsD1 = Bs + 2048 + wave * 512;

  for (int k0 = 0; k0 < K; k0 += 32) {
    __syncthreads();
    gl_lds16(Ap0 + k0, AsD0);
    gl_lds16(Ap1 + k0, AsD1);
    gl_lds16(Bp0 + k0, BsD0);
    gl_lds16(Bp1 + k0, BsD1);
    __syncthreads();
    bf16x8 af[4], bf[4];
#pragma unroll
    for (int mi = 0; mi < 4; ++mi)
      af[mi] = *(const bf16x8*)&As[(wr + mi * 16 + l16) * 32 + quad * 8];
#pragma unroll
    for (int ni = 0; ni < 4; ++ni)
      bf[ni] = *(const bf16x8*)&Bs[(wc + ni * 16 + l16) * 32 + quad * 8];
#pragma unroll
    for (int mi = 0; mi < 4; ++mi)
#pragma unroll
      for (int ni = 0; ni < 4; ++ni)
        acc[mi][ni] = __builtin_amdgcn_mfma_f32_16x16x32_bf16(af[mi], bf[ni], acc[mi][ni], 0, 0, 0);
  }
#pragma unroll
  for (int mi = 0; mi < 4; ++mi)
#pragma unroll
    for (int ni = 0; ni < 4; ++ni)
#pragma unroll
      for (int r = 0; r < 4; ++r) {
        long row = row0 + wr + mi * 16 + quad * 4 + r;
        long col = col0 + wc + ni * 16 + l16;
        float v = acc[mi][ni][r];
        if (OUT_BF16) ((unsigned short*)Cout)[row * N + col] = f2b(v);
        else          ((float*)Cout)[row * N + col] = v;
      }
}

// ------------------------------------------- RoPE + sym int8 quant-dequant + split
// qkv[2048][6144] bf16 -> Qb[32][2048][128], Kb[8][2048][128], Vb[8][2048][128]
__global__ __launch_bounds__(256) void postproc(const unsigned short* __restrict__ qkv,
                                                const int* __restrict__ pos_ids,
                                                unsigned short* __restrict__ Qb,
                                                unsigned short* __restrict__ Kb,
                                                unsigned short* __restrict__ Vb) {
  const int s = blockIdx.x;
  const int lane = threadIdx.x & 63, wave = threadIdx.x >> 6;
  const float pos = (float)pos_ids[s];
  // inv_freq = 10000^(-lane/64) = exp(-lane * ln(10000)/64); pair (d, d+64)
  const float invf = expf(-(float)lane * 0.14391156831212787f);
  const float ang = pos * invf;
  const float ca = cosf(ang), sa = sinf(ang);

  for (int r = wave; r < 48; r += 4) {
    if (r < 32) {                 // Q head r: rope only
      const unsigned short* src = qkv + (long)s * QKV_N + r * HD;
      float x0 = b2f(src[lane]), x1 = b2f(src[lane + 64]);
      unsigned short* dst = Qb + ((long)r * S_LEN + s) * HD;
      dst[lane]      = f2b(x0 * ca - x1 * sa);
      dst[lane + 64] = f2b(x1 * ca + x0 * sa);
    } else if (r < 40) {          // K head r-32: rope then quant-dequant
      int h = r - 32;
      const unsigned short* src = qkv + (long)s * QKV_N + 4096 + h * HD;
      float x0 = b2f(src[lane]), x1 = b2f(src[lane + 64]);
      float y0 = x0 * ca - x1 * sa;
      float y1 = x1 * ca + x0 * sa;
      float m = fmaxf(fabsf(y0), fabsf(y1));
      for (int off = 32; off; off >>= 1) m = fmaxf(m, __shfl_xor(m, off, 64));
      float scale = fmaxf(m / 127.0f, 1e-9f);
      float q0 = fminf(fmaxf(rintf(y0 / scale), -128.f), 127.f);
      float q1 = fminf(fmaxf(rintf(y1 / scale), -128.f), 127.f);
      unsigned short* dst = Kb + ((long)h * S_LEN + s) * HD;
      dst[lane]      = f2b(q0 * scale);
      dst[lane + 64] = f2b(q1 * scale);
    } else {                      // V head r-40: quant-dequant only
      int h = r - 40;
      const unsigned short* src = qkv + (long)s * QKV_N + 5120 + h * HD;
      float x0 = b2f(src[lane]), x1 = b2f(src[lane + 64]);
      float m = fmaxf(fabsf(x0), fabsf(x1));
      for (int off = 32; off; off >>= 1) m = fmaxf(m, __shfl_xor(m, off, 64));
      float scale = fmaxf(m / 127.0f, 1e-9f);
      float q0 = fminf(fmaxf(rintf(x0 / scale), -128.f), 127.f);
      float q1 = fminf(fmaxf(rintf(x1 / scale), -128.f), 127.f);
      unsigned short* dst = Vb + ((long)h * S_LEN + s) * HD;
      dst[lane]      = f2b(q0 * scale);
      dst[lane + 64] = f2b(q1 * scale);
    }
  }
}

// -------------------------------------------------- V transpose: [h][s][d]->[h][d][s]
__global__ __launch_bounds__(256) void transpose_v(const unsigned short* __restrict__ Vb,
                                                   unsigned short* __restrict__ Vtb) {
  __shared__ unsigned short t[64][136];
  const int h = blockIdx.x >> 5, st = blockIdx.x & 31;
  const int tid = threadIdx.x;
  const long vbase = (long)h * S_LEN * HD;
#pragma unroll
  for (int p = 0; p < 8; ++p) {
    int e = p * 1024 + tid * 4;
    int sl = e >> 7, d = e & 127;
    ushort4 v = *(const ushort4*)(Vb + vbase + (long)(st * 64 + sl) * HD + d);
    t[sl][d] = v.x; t[sl][d + 1] = v.y; t[sl][d + 2] = v.z; t[sl][d + 3] = v.w;
  }
  __syncthreads();
  const long tbase = (long)h * HD * S_LEN;
#pragma unroll
  for (int p = 0; p < 8; ++p) {
    int o = p * 1024 + tid * 4;
    int d = o >> 6, sl = o & 63;
    ushort4 v;
    v.x = t[sl][d]; v.y = t[sl + 1][d]; v.z = t[sl + 2][d]; v.w = t[sl + 3][d];
    *(ushort4*)(Vtb + tbase + (long)d * S_LEN + st * 64 + sl) = v;
  }
}

// ------------------------------------------------------------- flash attention
// BARRIER-FREE: block = (head, 128-row q-tile), 4 waves x 32 q-rows.
// K ([key][d], B^T layout) and Vt ([d][key]) fragments are loaded directly
// global->VGPR per MFMA group; L2 absorbs the in-block 4x re-read. P does a
// wave-local LDS round-trip (C-layout write -> A-layout read, rows owned by
// the writing wave), so NO __syncthreads exists in the kernel: the compiler
// emits fine-grained vmcnt/lgkmcnt instead of a full drain per tile.
// Complementary qt pairing: under either {2c,2c+1} or {c,c+256} co-residency
// the two blocks on a CU have qt and 15-qt (17 iterations each pair).
__global__ __launch_bounds__(256, 2) void attn_kernel(const unsigned short* __restrict__ Qb,
                                                      const unsigned short* __restrict__ Kb,
                                                      const unsigned short* __restrict__ Vtb,
                                                      unsigned short* __restrict__ Ob) {
  __shared__ __align__(16) unsigned short Ps[128 * 136];  // P, stride 136 (+8 pad)

  const int bx = blockIdx.x;
  const int p8 = bx & 1;
  const int g = (bx >> 1) & 7;
  const int b8 = bx >> 8;
  const int qt = (p8 ^ b8) ? (15 - g) : g;
  const int h = ((bx >> 4) & 15) + 16 * b8;
  const int hk = h >> 2;                        // GQA: 4 q-heads per kv-head
  const int tid = threadIdx.x;
  const int lane = tid & 63, wave = tid >> 6;
  const int quad = lane >> 4, l16 = lane & 15;

  // Q fragments for this wave's 32 rows (A-operand layout), from global
  bf16x8 qf[2][4];
  {
    const unsigned short* qb =
        Qb + ((long)h * S_LEN + qt * 128 + wave * 32 + l16) * HD + quad * 8;
#pragma unroll
    for (int mi = 0; mi < 2; ++mi)
#pragma unroll
      for (int ks = 0; ks < 4; ++ks)
        qf[mi][ks] = *(const bf16x8*)(qb + mi * 16 * HD + ks * 32);
  }

  f32x4 O[2][8] = {};
  float mrow[2][4], lrow[2][4];
#pragma unroll
  for (int mi = 0; mi < 2; ++mi)
#pragma unroll
    for (int r = 0; r < 4; ++r) { mrow[mi][r] = -1e30f; lrow[mi][r] = 0.f; }

  const unsigned short* Kbase = Kb + (long)hk * S_LEN * HD;
  const unsigned short* Vbase = Vtb + (long)hk * HD * S_LEN;
  const float sscale = 0.08838834764831845f;  // 1/sqrt(128)

  for (int kt = 0; kt <= qt; ++kt) {
    const unsigned short* Kt = Kbase + (long)kt * 128 * HD;

    // S = Q K^T : B-fragments straight from global (row = key, 16B x 4 ks)
    f32x4 S[2][8] = {};
#pragma unroll
    for (int ni = 0; ni < 8; ++ni) {
      const unsigned short* kr = Kt + (ni * 16 + l16) * HD + quad * 8;
      bf16x8 kf0 = *(const bf16x8*)(kr);
      bf16x8 kf1 = *(const bf16x8*)(kr + 32);
      bf16x8 kf2 = *(const bf16x8*)(kr + 64);
      bf16x8 kf3 = *(const bf16x8*)(kr + 96);
      S[0][ni] = __builtin_amdgcn_mfma_f32_16x16x32_bf16(qf[0][0], kf0, S[0][ni], 0, 0, 0);
      S[1][ni] = __builtin_amdgcn_mfma_f32_16x16x32_bf16(qf[1][0], kf0, S[1][ni], 0, 0, 0);
      S[0][ni] = __builtin_amdgcn_mfma_f32_16x16x32_bf16(qf[0][1], kf1, S[0][ni], 0, 0, 0);
      S[1][ni] = __builtin_amdgcn_mfma_f32_16x16x32_bf16(qf[1][1], kf1, S[1][ni], 0, 0, 0);
      S[0][ni] = __builtin_amdgcn_mfma_f32_16x16x32_bf16(qf[0][2], kf2, S[0][ni], 0, 0, 0);
      S[1][ni] = __builtin_amdgcn_mfma_f32_16x16x32_bf16(qf[1][2], kf2, S[1][ni], 0, 0, 0);
      S[0][ni] = __builtin_amdgcn_mfma_f32_16x16x32_bf16(qf[0][3], kf3, S[0][ni], 0, 0, 0);
      S[1][ni] = __builtin_amdgcn_mfma_f32_16x16x32_bf16(qf[1][3], kf3, S[1][ni], 0, 0, 0);
    }

    // scale + causal mask + row max
    const bool diag = (kt == qt);
    const int qrow_base = qt * 128 + wave * 32;
    float rmax[2][4];
#pragma unroll
    for (int mi = 0; mi < 2; ++mi)
#pragma unroll
      for (int r = 0; r < 4; ++r) rmax[mi][r] = -1e30f;
#pragma unroll
    for (int mi = 0; mi < 2; ++mi)
#pragma unroll
      for (int ni = 0; ni < 8; ++ni) {
        int col = kt * 128 + ni * 16 + l16;
#pragma unroll
        for (int r = 0; r < 4; ++r) {
          int row = qrow_base + mi * 16 + quad * 4 + r;
          float v = S[mi][ni][r] * sscale;
          if (diag && col > row) v = -1e9f;
          S[mi][ni][r] = v;
          rmax[mi][r] = fmaxf(rmax[mi][r], v);
        }
      }
    float alpha[2][4], rsum[2][4];
#pragma unroll
    for (int mi = 0; mi < 2; ++mi)
#pragma unroll
      for (int r = 0; r < 4; ++r) {
        float v = rmax[mi][r];
        v = fmaxf(v, __shfl_xor(v, 1, 64));
        v = fmaxf(v, __shfl_xor(v, 2, 64));
        v = fmaxf(v, __shfl_xor(v, 4, 64));
        v = fmaxf(v, __shfl_xor(v, 8, 64));
        float mnew = fmaxf(mrow[mi][r], v);
        alpha[mi][r] = __expf(mrow[mi][r] - mnew);
        mrow[mi][r] = mnew;
        rsum[mi][r] = 0.f;
      }

    // P = exp(S - m) -> wave-local LDS rows (C-layout write), accumulate sums
#pragma unroll
    for (int mi = 0; mi < 2; ++mi)
#pragma unroll
      for (int ni = 0; ni < 8; ++ni)
#pragma unroll
        for (int r = 0; r < 4; ++r) {
          float p = __expf(S[mi][ni][r] - mrow[mi][r]);
          rsum[mi][r] += p;
          int prow = wave * 32 + mi * 16 + quad * 4 + r;
          int pcol = ni * 16 + l16;
          Ps[prow * 136 + pcol] = f2b(p);
        }
#pragma unroll
    for (int mi = 0; mi < 2; ++mi)
#pragma unroll
      for (int r = 0; r < 4; ++r) {
        float v = rsum[mi][r];
        v += __shfl_xor(v, 1, 64);
        v += __shfl_xor(v, 2, 64);
        v += __shfl_xor(v, 4, 64);
        v += __shfl_xor(v, 8, 64);
        lrow[mi][r] = lrow[mi][r] * alpha[mi][r] + v;
      }
#pragma unroll
    for (int mi = 0; mi < 2; ++mi)
#pragma unroll
      for (int ni = 0; ni < 8; ++ni)
#pragma unroll
        for (int r = 0; r < 4; ++r) O[mi][ni][r] *= alpha[mi][r];

    // O += P V : P A-frags from wave-local LDS, Vt B-frags straight from global
    bf16x8 pf[2][4];
#pragma unroll
    for (int mi = 0; mi < 2; ++mi)
#pragma unroll
      for (int ks2 = 0; ks2 < 4; ++ks2) {
        int prow = wave * 32 + mi * 16 + l16;
        pf[mi][ks2] = *(const bf16x8*)&Ps[prow * 136 + ks2 * 32 + quad * 8];
      }
#pragma unroll
    for (int ni = 0; ni < 8; ++ni) {
      const unsigned short* vr = Vbase + (long)(ni * 16 + l16) * S_LEN + kt * 128 + quad * 8;
      bf16x8 vf0 = *(const bf16x8*)(vr);
      bf16x8 vf1 = *(const bf16x8*)(vr + 32);
      bf16x8 vf2 = *(const bf16x8*)(vr + 64);
      bf16x8 vf3 = *(const bf16x8*)(vr + 96);
      O[0][ni] = __builtin_amdgcn_mfma_f32_16x16x32_bf16(pf[0][0], vf0, O[0][ni], 0, 0, 0);
      O[1][ni] = __builtin_amdgcn_mfma_f32_16x16x32_bf16(pf[1][0], vf0, O[1][ni], 0, 0, 0);
      O[0][ni] = __builtin_amdgcn_mfma_f32_16x16x32_bf16(pf[0][1], vf1, O[0][ni], 0, 0, 0);
      O[1][ni] = __builtin_amdgcn_mfma_f32_16x16x32_bf16(pf[1][1], vf1, O[1][ni], 0, 0, 0);
      O[0][ni] = __builtin_amdgcn_mfma_f32_16x16x32_bf16(pf[0][2], vf2, O[0][ni], 0, 0, 0);
      O[1][ni] = __builtin_amdgcn_mfma_f32_16x16x32_bf16(pf[1][2], vf2, O[1][ni], 0, 0, 0);
      O[0][ni] = __builtin_amdgcn_mfma_f32_16x16x32_bf16(pf[0][3], vf3, O[0][ni], 0, 0, 0);
      O[1][ni] = __builtin_amdgcn_mfma_f32_16x16x32_bf16(pf[1][3], vf3, O[1][ni], 0, 0, 0);
    }
  }

  // normalize + store bf16 at [s][h*128+d]
#pragma unroll
  for (int mi = 0; mi < 2; ++mi)
#pragma unroll
    for (int r = 0; r < 4; ++r) {
      float inv = 1.0f / lrow[mi][r];
      long srow = qt * 128 + wave * 32 + mi * 16 + quad * 4 + r;
#pragma unroll
      for (int ni = 0; ni < 8; ++ni) {
        long col = (long)h * HD + ni * 16 + l16;
        Ob[srow * (long)HID + col] = f2b(O[mi][ni][r] * inv);
      }
    }
}

// ---------------------------------------------------------------------------
extern "C" void kernel_launch(void* const* d_in, const int* in_sizes, int n_in,
                              void* d_out, int out_size, void* d_ws, size_t ws_size,
                              hipStream_t stream) {
  const float* hidden = (const float*)d_in[0];
  const float* wq = (const float*)d_in[1];
  const float* wk = (const float*)d_in[2];
  const float* wv = (const float*)d_in[3];
  const float* wo = (const float*)d_in[4];
  const int* pos = (const int*)d_in[5];
  float* out = (float*)d_out;

  // workspace layout (bytes); total 138,412,032. Overlays: Qb=hid_b (hid dead
  // after GEMM1), attn_b=qkv_b (qkv dead after postproc).
  char* ws = (char*)d_ws;
  unsigned short* wqkv_b = (unsigned short*)(ws);               // 50,331,648
  unsigned short* wo_b   = (unsigned short*)(ws + 50331648);    // 33,554,432
  unsigned short* hid_b  = (unsigned short*)(ws + 83886080);    // 16,777,216
  unsigned short* qkv_b  = (unsigned short*)(ws + 100663296);   // 25,165,824
  unsigned short* Kb     = (unsigned short*)(ws + 125829120);   //  4,194,304
  unsigned short* Vb     = (unsigned short*)(ws + 130023424);   //  4,194,304
  unsigned short* Vtb    = (unsigned short*)(ws + 134217728);   //  4,194,304
  unsigned short* Qb     = hid_b;
  unsigned short* attn_b = qkv_b;

  cast_kernel<<<8388608 / 1024, 256, 0, stream>>>(hidden, hid_b, 8388608 / 4);
  cast_kernel<<<16777216 / 1024, 256, 0, stream>>>(wq, wqkv_b, 16777216 / 4);
  cast_kernel<<<4194304 / 1024, 256, 0, stream>>>(wk, wqkv_b + 16777216, 4194304 / 4);
  cast_kernel<<<4194304 / 1024, 256, 0, stream>>>(wv, wqkv_b + 20971520, 4194304 / 4);
  cast_kernel<<<16777216 / 1024, 256, 0, stream>>>(wo, wo_b, 16777216 / 4);

  gemm_bt<1><<<dim3(QKV_N / 128, S_LEN / 128), 256, 0, stream>>>(
      hid_b, wqkv_b, (void*)qkv_b, S_LEN, QKV_N, HID);

  postproc<<<S_LEN, 256, 0, stream>>>(qkv_b, pos, Qb, Kb, Vb);
  transpose_v<<<NKV * 32, 256, 0, stream>>>(Vb, Vtb);
  attn_kernel<<<NH * 16, 256, 0, stream>>>(Qb, Kb, Vtb, attn_b);

  gemm_bt<0><<<dim3(HID / 128, S_LEN / 128), 256, 0, stream>>>(
      attn_b, wo_b, (void*)out, S_LEN, HID, HID);
}